// Round 3
// baseline (196.513 us; speedup 1.0000x reference)
//
#include <hip/hip_runtime.h>
#include <math.h>

constexpr int Bn = 1024, DH = 2048, K1 = 4096, DO = 1024, NL = 128;

typedef __bf16 bf16x8 __attribute__((ext_vector_type(8)));
typedef short  s16x8  __attribute__((ext_vector_type(8)));
typedef float  f32x4  __attribute__((ext_vector_type(4)));

__device__ __forceinline__ unsigned short f2bf(float f) {
  union { float f; unsigned u; } v; v.f = f;
  unsigned r = v.u + 0x7FFFu + ((v.u >> 16) & 1u);  // RNE
  return (unsigned short)(r >> 16);
}

// ---------- convert kernels ----------

__global__ __launch_bounds__(256)
void concat_relu_bf16(const float* __restrict__ sbj, const float* __restrict__ obj,
                      unsigned short* __restrict__ out) {
  const int t = blockIdx.x * 256 + threadIdx.x;
  const int m = t >> 9;
  const int k = (t & 511) << 3;
  const float* src = (k < DH) ? sbj + (size_t)m * DH + k
                              : obj + (size_t)m * DH + (k - DH);
  const float4 a = ((const float4*)src)[0];
  const float4 b = ((const float4*)src)[1];
  uint4 o;
  o.x = (unsigned)f2bf(fmaxf(a.x, 0.f)) | ((unsigned)f2bf(fmaxf(a.y, 0.f)) << 16);
  o.y = (unsigned)f2bf(fmaxf(a.z, 0.f)) | ((unsigned)f2bf(fmaxf(a.w, 0.f)) << 16);
  o.z = (unsigned)f2bf(fmaxf(b.x, 0.f)) | ((unsigned)f2bf(fmaxf(b.y, 0.f)) << 16);
  o.w = (unsigned)f2bf(fmaxf(b.z, 0.f)) | ((unsigned)f2bf(fmaxf(b.w, 0.f)) << 16);
  *(uint4*)&out[(size_t)m * K1 + k] = o;
}

__global__ __launch_bounds__(256)
void transp_bf16(const float* __restrict__ in, unsigned short* __restrict__ out,
                 int R, int C) {
  __shared__ float tl[64][65];
  const int tid = threadIdx.x;
  const int r0 = blockIdx.y * 64, c0 = blockIdx.x * 64;
  {
    const int rr = tid >> 4, cc = (tid & 15) * 4;
    #pragma unroll
    for (int i = 0; i < 4; ++i) {
      const float4 v = *(const float4*)&in[(size_t)(r0 + rr + i * 16) * C + c0 + cc];
      tl[rr + i * 16][cc + 0] = v.x; tl[rr + i * 16][cc + 1] = v.y;
      tl[rr + i * 16][cc + 2] = v.z; tl[rr + i * 16][cc + 3] = v.w;
    }
  }
  __syncthreads();
  {
    const int r4 = (tid & 15) * 4;
    #pragma unroll
    for (int i = 0; i < 4; ++i) {
      const int cr = i * 16 + (tid >> 4);
      uint2 o;
      o.x = (unsigned)f2bf(tl[r4 + 0][cr]) | ((unsigned)f2bf(tl[r4 + 1][cr]) << 16);
      o.y = (unsigned)f2bf(tl[r4 + 2][cr]) | ((unsigned)f2bf(tl[r4 + 3][cr]) << 16);
      *(uint2*)&out[(size_t)(c0 + cr) * R + r0 + r4] = o;
    }
  }
}

// ---------- MFMA GEMM: 512 thr (8 waves), 64x64 tile, split-K across waves,
// explicit LDS double-buffer so the vmcnt(0) barrier drain overlaps compute ----
template <int K, bool RELU, typename OUTT>
__global__ __launch_bounds__(512)
void mfma_gemm64(const unsigned short* __restrict__ A,
                 const unsigned short* __restrict__ Bt,
                 const float* __restrict__ bias,
                 OUTT* __restrict__ out, int M, int N) {
  __shared__ __align__(16) unsigned short Asm[2][64 * 256];  // 2 x 32 KB
  __shared__ __align__(16) unsigned short Bsm[2][64 * 256];  // 2 x 32 KB

  const int tid = threadIdx.x;
  const int w = tid >> 6, l = tid & 63;
  const int m0 = blockIdx.y * 64, n0 = blockIdx.x * 64;

  f32x4 acc[4][4] = {};

  // stage one 64x256 A tile + 64x256 B tile into buffer `buf` (async DMA)
  auto stage = [&](int buf, int ko) {
    #pragma unroll
    for (int i = 0; i < 4; ++i) {
      const int c = i * 512 + tid;
      const int m = c >> 5, kc = c & 31;
      const int kcg = (kc & 24) | ((kc & 7) ^ (m & 7));
      __builtin_amdgcn_global_load_lds(
          (const __attribute__((address_space(1))) unsigned int*)(A + (size_t)(m0 + m) * K + ko + kcg * 8),
          (__attribute__((address_space(3))) unsigned int*)&Asm[buf][(i * 512 + w * 64) * 8],
          16, 0, 0);
    }
    #pragma unroll
    for (int i = 0; i < 4; ++i) {
      const int c = i * 512 + tid;
      const int n = c >> 5, kc = c & 31;
      const int kcg = (kc & 24) | ((kc & 7) ^ (n & 7));
      __builtin_amdgcn_global_load_lds(
          (const __attribute__((address_space(1))) unsigned int*)(Bt + (size_t)(n0 + n) * K + ko + kcg * 8),
          (__attribute__((address_space(3))) unsigned int*)&Bsm[buf][(i * 512 + w * 64) * 8],
          16, 0, 0);
    }
  };

  constexpr int NIT = K / 256;
  stage(0, 0);
  __syncthreads();

  for (int it = 0; it < NIT; ++it) {
    if (it + 1 < NIT) stage((it + 1) & 1, (it + 1) * 256);  // prefetch next tile
    const int buf = it & 1;
    // wave w owns k-chunk [w*32, w*32+32) of this 256-k block
    const int kcq = w * 4 + (l >> 4);  // logical k-chunk-of-8, 0..31
    bf16x8 af[4], bfr[4];
    #pragma unroll
    for (int i = 0; i < 4; ++i) {
      const int r = i * 16 + (l & 15);
      const int kca = (kcq & 24) | ((kcq & 7) ^ (r & 7));
      af[i]  = __builtin_bit_cast(bf16x8, *(const s16x8*)&Asm[buf][r * 256 + kca * 8]);
      bfr[i] = __builtin_bit_cast(bf16x8, *(const s16x8*)&Bsm[buf][r * 256 + kca * 8]);
    }
    #pragma unroll
    for (int i = 0; i < 4; ++i)
      #pragma unroll
      for (int j = 0; j < 4; ++j)
        acc[i][j] = __builtin_amdgcn_mfma_f32_16x16x32_bf16(af[i], bfr[j], acc[i][j], 0, 0, 0);
    __syncthreads();  // drains prefetch (compute time already elapsed) + guards buf reuse
  }

  // ---- 8-way split-K tree reduction in LDS (reuse Asm: 64 KB) ----
  float* red = (float*)&Asm[0][0];
  auto writeacc = [&](float* dst) {
    #pragma unroll
    for (int i = 0; i < 4; ++i)
      #pragma unroll
      for (int j = 0; j < 4; ++j)
        *(f32x4*)&dst[((i * 4 + j) * 64 + l) * 4] = acc[i][j];
  };
  auto addacc = [&](const float* src) {
    #pragma unroll
    for (int i = 0; i < 4; ++i)
      #pragma unroll
      for (int j = 0; j < 4; ++j)
        acc[i][j] += *(const f32x4*)&src[((i * 4 + j) * 64 + l) * 4];
  };
  if (w >= 4) writeacc(red + (w - 4) * 4096);
  __syncthreads();
  if (w < 4) addacc(red + w * 4096);
  __syncthreads();
  if (w == 2 || w == 3) writeacc(red + (w - 2) * 4096);
  __syncthreads();
  if (w < 2) addacc(red + w * 4096);
  __syncthreads();
  if (w == 1) writeacc(red);
  __syncthreads();
  if (w != 0) return;
  addacc(red);

  // ---- epilogue (wave 0): C/D layout col=l&15, row=(l>>4)*4+r ----
  #pragma unroll
  for (int j = 0; j < 4; ++j) {
    const int n = n0 + j * 16 + (l & 15);
    const float bb = bias[n];
    #pragma unroll
    for (int i = 0; i < 4; ++i) {
      #pragma unroll
      for (int r = 0; r < 4; ++r) {
        const int m = m0 + i * 16 + (l >> 4) * 4 + r;
        float v = acc[i][j][r] + bb;
        if (RELU) v = fmaxf(v, 0.f);
        if constexpr (sizeof(OUTT) == 2)
          out[(size_t)m * N + n] = (OUTT)f2bf(v);
        else
          out[(size_t)m * N + n] = (OUTT)v;
      }
    }
  }
}

// ---------- scores: d-split partial kernel + finalize ----------
// Block: 32 batch x 128 labels x 64-d chunk. Grid (32 b-tiles, 16 d-chunks) = 512.
// Per-thread micro-tile 2b x 8l (16 accumulators), LDS staged d-major.
__global__ __launch_bounds__(256)
void score_partial(const float* __restrict__ emb, const float* __restrict__ labels,
                   float* __restrict__ sc2) {
  __shared__ float es[64][33];   // [d][b]  8.4 KB
  __shared__ float ls[64][132];  // [d][l]  33.8 KB (132: 16B-aligned rows, bank-clean)
  const int tid = threadIdx.x;
  const int b0 = blockIdx.x * 32;
  const int d0 = blockIdx.y * 64;

  // stage emb chunk: 32 rows x 64 d
  #pragma unroll
  for (int i = 0; i < 2; ++i) {
    const int fi = tid + i * 256;          // 0..511
    const int b = fi >> 4, dq = fi & 15;
    const float4 v = *(const float4*)&emb[(size_t)(b0 + b) * DO + d0 + dq * 4];
    es[dq * 4 + 0][b] = v.x; es[dq * 4 + 1][b] = v.y;
    es[dq * 4 + 2][b] = v.z; es[dq * 4 + 3][b] = v.w;
  }
  // stage label chunk: 128 rows x 64 d
  #pragma unroll
  for (int i = 0; i < 8; ++i) {
    const int fi = tid + i * 256;          // 0..2047
    const int lr = fi >> 4, dq = fi & 15;
    const float4 v = *(const float4*)&labels[(size_t)lr * DO + d0 + dq * 4];
    ls[dq * 4 + 0][lr] = v.x; ls[dq * 4 + 1][lr] = v.y;
    ls[dq * 4 + 2][lr] = v.z; ls[dq * 4 + 3][lr] = v.w;
  }
  __syncthreads();

  const int tb = tid & 15;   // b-pair group
  const int tl = tid >> 4;   // label-octet group
  float acc[2][8] = {};

  for (int dd = 0; dd < 64; ++dd) {
    const float e0 = es[dd][tb * 2 + 0];
    const float e1 = es[dd][tb * 2 + 1];
    const float4 l0 = *(const float4*)&ls[dd][tl * 8];
    const float4 l1 = *(const float4*)&ls[dd][tl * 8 + 4];
    const float lv[8] = {l0.x, l0.y, l0.z, l0.w, l1.x, l1.y, l1.z, l1.w};
    #pragma unroll
    for (int j = 0; j < 8; ++j) {
      float t0 = fmaxf(lv[j] - e0, 0.f); acc[0][j] = fmaf(t0, t0, acc[0][j]);
      float t1 = fmaxf(lv[j] - e1, 0.f); acc[1][j] = fmaf(t1, t1, acc[1][j]);
    }
  }

  #pragma unroll
  for (int i = 0; i < 2; ++i)
    #pragma unroll
    for (int j = 0; j < 8; ++j)
      atomicAdd(&sc2[(size_t)(b0 + tb * 2 + i) * NL + tl * 8 + j], acc[i][j]);
}

__global__ __launch_bounds__(256)
void score_finalize(const float* __restrict__ sc2, float* __restrict__ out) {
  const int idx = (blockIdx.x * 256 + threadIdx.x) * 4;
  const float4 v = *(const float4*)&sc2[idx];
  float4 o = {-sqrtf(v.x), -sqrtf(v.y), -sqrtf(v.z), -sqrtf(v.w)};
  *(float4*)&out[idx] = o;
}

extern "C" void kernel_launch(void* const* d_in, const int* in_sizes, int n_in,
                              void* d_out, int out_size, void* d_ws, size_t ws_size,
                              hipStream_t stream) {
  const float* sbj  = (const float*)d_in[0];
  const float* obj  = (const float*)d_in[1];
  const float* W1   = (const float*)d_in[2];
  const float* b1   = (const float*)d_in[3];
  const float* W2   = (const float*)d_in[4];
  const float* b2   = (const float*)d_in[5];
  const float* labs = (const float*)d_in[6];
  float* scores = (float*)d_out;

  char* ws = (char*)d_ws;
  unsigned short* Abf = (unsigned short*)(ws);                // 8 MB [1024][4096]
  unsigned short* W1t = (unsigned short*)(ws + (8u << 20));   // 8 MB [1024][4096]
  unsigned short* W2t = (unsigned short*)(ws + (16u << 20));  // 2 MB [1024][1024]
  unsigned short* H   = (unsigned short*)(ws + (18u << 20));  // 2 MB [1024][1024]
  float*          E   = (float*)(ws + (20u << 20));           // 4 MB [1024][1024]
  float*          sc2 = (float*)(ws + (24u << 20));           // 512 KB [1024][128]

  dim3 blk(256);
  hipMemsetAsync(sc2, 0, (size_t)Bn * NL * sizeof(float), stream);
  concat_relu_bf16<<<dim3(2048), blk, 0, stream>>>(sbj, obj, Abf);
  transp_bf16<<<dim3(DO / 64, K1 / 64), blk, 0, stream>>>(W1, W1t, K1, DO);
  transp_bf16<<<dim3(DO / 64, DO / 64), blk, 0, stream>>>(W2, W2t, DO, DO);
  mfma_gemm64<K1, true, unsigned short><<<dim3(16, 16), dim3(512), 0, stream>>>(
      Abf, W1t, b1, H, Bn, DO);
  mfma_gemm64<DO, false, float><<<dim3(16, 16), dim3(512), 0, stream>>>(
      H, W2t, b2, E, Bn, DO);
  score_partial<<<dim3(32, 16), blk, 0, stream>>>(E, labs, sc2);
  score_finalize<<<dim3(128), blk, 0, stream>>>(sc2, scores);
}

// Round 4
// 156.490 us; speedup vs baseline: 1.2557x; 1.2557x over previous
//
#include <hip/hip_runtime.h>
#include <math.h>

constexpr int Bn = 1024, DH = 2048, K1 = 4096, DO = 1024, NL = 128;
constexpr int MN = Bn * DO;  // 1M elements

typedef __bf16 bf16x8 __attribute__((ext_vector_type(8)));
typedef short  s16x8  __attribute__((ext_vector_type(8)));
typedef float  f32x4  __attribute__((ext_vector_type(4)));

__device__ __forceinline__ unsigned short f2bf(float f) {
  union { float f; unsigned u; } v; v.f = f;
  unsigned r = v.u + 0x7FFFu + ((v.u >> 16) & 1u);  // RNE
  return (unsigned short)(r >> 16);
}

// ---------- converts ----------

__global__ __launch_bounds__(256)
void concat_relu_bf16(const float* __restrict__ sbj, const float* __restrict__ obj,
                      unsigned short* __restrict__ out) {
  const int t = blockIdx.x * 256 + threadIdx.x;
  const int m = t >> 9;
  const int k = (t & 511) << 3;
  const float* src = (k < DH) ? sbj + (size_t)m * DH + k
                              : obj + (size_t)m * DH + (k - DH);
  const float4 a = ((const float4*)src)[0];
  const float4 b = ((const float4*)src)[1];
  uint4 o;
  o.x = (unsigned)f2bf(fmaxf(a.x, 0.f)) | ((unsigned)f2bf(fmaxf(a.y, 0.f)) << 16);
  o.y = (unsigned)f2bf(fmaxf(a.z, 0.f)) | ((unsigned)f2bf(fmaxf(a.w, 0.f)) << 16);
  o.z = (unsigned)f2bf(fmaxf(b.x, 0.f)) | ((unsigned)f2bf(fmaxf(b.y, 0.f)) << 16);
  o.w = (unsigned)f2bf(fmaxf(b.z, 0.f)) | ((unsigned)f2bf(fmaxf(b.w, 0.f)) << 16);
  *(uint4*)&out[(size_t)m * K1 + k] = o;
}

// One dispatch transposes both W1 (by 0..63) and W2 (by 64..79). C = 1024 both.
__global__ __launch_bounds__(256)
void transp_all(const float* __restrict__ W1, const float* __restrict__ W2,
                unsigned short* __restrict__ W1t, unsigned short* __restrict__ W2t) {
  __shared__ float tl[64][65];
  const int tid = threadIdx.x;
  int by = blockIdx.y;
  const float* in; unsigned short* out; int R;
  if (by < 64) { in = W1; out = W1t; R = K1; }
  else         { in = W2; out = W2t; R = DO; by -= 64; }
  const int r0 = by * 64, c0 = blockIdx.x * 64;
  {
    const int rr = tid >> 4, cc = (tid & 15) * 4;
    #pragma unroll
    for (int i = 0; i < 4; ++i) {
      const float4 v = *(const float4*)&in[(size_t)(r0 + rr + i * 16) * DO + c0 + cc];
      tl[rr + i * 16][cc + 0] = v.x; tl[rr + i * 16][cc + 1] = v.y;
      tl[rr + i * 16][cc + 2] = v.z; tl[rr + i * 16][cc + 3] = v.w;
    }
  }
  __syncthreads();
  {
    const int r4 = (tid & 15) * 4;
    #pragma unroll
    for (int i = 0; i < 4; ++i) {
      const int cr = i * 16 + (tid >> 4);
      uint2 o;
      o.x = (unsigned)f2bf(tl[r4 + 0][cr]) | ((unsigned)f2bf(tl[r4 + 1][cr]) << 16);
      o.y = (unsigned)f2bf(tl[r4 + 2][cr]) | ((unsigned)f2bf(tl[r4 + 3][cr]) << 16);
      *(uint2*)&out[(size_t)(c0 + cr) * R + r0 + r4] = o;
    }
  }
}

// ---------- MFMA GEMM: tile (WM*32)x(WN*32), 4 waves in 2x2, BK=64 dbuf,
// block-level split-K via blockIdx.z; writes fp32 partials P[z][1024][1024] ----
template <int WM, int WN, int KSLICE>
__global__ __launch_bounds__(256)
void mfma_gemm(const unsigned short* __restrict__ A,
               const unsigned short* __restrict__ Bt,
               float* __restrict__ P, int K) {
  constexpr int TM = WM * 32, TN = WN * 32;
  __shared__ __align__(16) unsigned short LA[2][TM * 64];
  __shared__ __align__(16) unsigned short LB[2][TN * 64];
  const int tid = threadIdx.x;
  const int w = tid >> 6, l = tid & 63;
  const int m0 = blockIdx.y * TM, n0 = blockIdx.x * TN;
  const int kb = blockIdx.z * KSLICE;

  f32x4 acc[WM][WN] = {};

  auto stage = [&](int buf, int k0) {
    #pragma unroll
    for (int i = 0; i < TM * 8 / 256; ++i) {
      const int flat = i * 256 + tid, row = flat >> 3, kc = flat & 7;
      const int kcg = kc ^ (row & 7);
      __builtin_amdgcn_global_load_lds(
          (const __attribute__((address_space(1))) unsigned int*)(A + (size_t)(m0 + row) * K + k0 + kcg * 8),
          (__attribute__((address_space(3))) unsigned int*)&LA[buf][(i * 256 + w * 64) * 8],
          16, 0, 0);
    }
    #pragma unroll
    for (int i = 0; i < TN * 8 / 256; ++i) {
      const int flat = i * 256 + tid, row = flat >> 3, kc = flat & 7;
      const int kcg = kc ^ (row & 7);
      __builtin_amdgcn_global_load_lds(
          (const __attribute__((address_space(1))) unsigned int*)(Bt + (size_t)(n0 + row) * K + k0 + kcg * 8),
          (__attribute__((address_space(3))) unsigned int*)&LB[buf][(i * 256 + w * 64) * 8],
          16, 0, 0);
    }
  };

  constexpr int NIT = KSLICE / 64;
  stage(0, kb);
  __syncthreads();

  for (int it = 0; it < NIT; ++it) {
    if (it + 1 < NIT) stage((it + 1) & 1, kb + (it + 1) * 64);
    const int buf = it & 1;
    #pragma unroll
    for (int s = 0; s < 2; ++s) {
      const int slot = (s * 4 + (l >> 4)) ^ (l & 7);  // r&7 == l&7 for all frag rows
      bf16x8 af[WM], bfr[WN];
      #pragma unroll
      for (int i = 0; i < WM; ++i) {
        const int r = (w >> 1) * WM * 16 + i * 16 + (l & 15);
        af[i] = __builtin_bit_cast(bf16x8, *(const s16x8*)&LA[buf][r * 64 + slot * 8]);
      }
      #pragma unroll
      for (int j = 0; j < WN; ++j) {
        const int rr = (w & 1) * WN * 16 + j * 16 + (l & 15);
        bfr[j] = __builtin_bit_cast(bf16x8, *(const s16x8*)&LB[buf][rr * 64 + slot * 8]);
      }
      #pragma unroll
      for (int i = 0; i < WM; ++i)
        #pragma unroll
        for (int j = 0; j < WN; ++j)
          acc[i][j] = __builtin_amdgcn_mfma_f32_16x16x32_bf16(af[i], bfr[j], acc[i][j], 0, 0, 0);
    }
    __syncthreads();
  }

  // store fp32 partials (C/D: col=l&15 -> n, row=(l>>4)*4+r -> m)
  float* Pz = P + (size_t)blockIdx.z * MN;
  #pragma unroll
  for (int i = 0; i < WM; ++i) {
    #pragma unroll
    for (int r = 0; r < 4; ++r) {
      const int m = m0 + (w >> 1) * WM * 16 + i * 16 + (l >> 4) * 4 + r;
      #pragma unroll
      for (int j = 0; j < WN; ++j) {
        const int n = n0 + (w & 1) * WN * 16 + j * 16 + (l & 15);
        Pz[(size_t)m * DO + n] = acc[i][j][r];
      }
    }
  }
}

// ---------- combine: out = act(sum_ks P + bias); one block per output row ----
template <int KS, bool RELU, bool OUT_BF16>
__global__ __launch_bounds__(256)
void combine(const float* __restrict__ P, const float* __restrict__ bias,
             void* __restrict__ out) {
  const int row = blockIdx.x, t = threadIdx.x;
  const size_t i4 = (size_t)row * 256 + t;
  f32x4 s = ((const f32x4*)P)[i4];
  #pragma unroll
  for (int c = 1; c < KS; ++c) s += ((const f32x4*)P)[(size_t)c * (MN / 4) + i4];
  const f32x4 bb = *(const f32x4*)&bias[t * 4];
  s += bb;
  if (RELU) {
    s[0] = fmaxf(s[0], 0.f); s[1] = fmaxf(s[1], 0.f);
    s[2] = fmaxf(s[2], 0.f); s[3] = fmaxf(s[3], 0.f);
  }
  if (OUT_BF16) {
    uint2 o;
    o.x = (unsigned)f2bf(s[0]) | ((unsigned)f2bf(s[1]) << 16);
    o.y = (unsigned)f2bf(s[2]) | ((unsigned)f2bf(s[3]) << 16);
    *(uint2*)((unsigned short*)out + (size_t)row * DO + t * 4) = o;
  } else {
    *(f32x4*)((float*)out + (size_t)row * DO + t * 4) = s;
  }
}

// ---------- scores: d-split partials (plain stores) + reduce ----------
// Block: 32 batch x 128 labels x 64-d chunk. Grid (32, 16) = 512 blocks.
__global__ __launch_bounds__(256)
void score_partial(const float* __restrict__ emb, const float* __restrict__ labels,
                   float* __restrict__ SP) {
  __shared__ float es[64][33];   // [d][b]
  __shared__ float ls[64][132];  // [d][l]
  const int tid = threadIdx.x;
  const int b0 = blockIdx.x * 32;
  const int d0 = blockIdx.y * 64;

  #pragma unroll
  for (int i = 0; i < 2; ++i) {
    const int fi = tid + i * 256;
    const int b = fi >> 4, dq = fi & 15;
    const float4 v = *(const float4*)&emb[(size_t)(b0 + b) * DO + d0 + dq * 4];
    es[dq * 4 + 0][b] = v.x; es[dq * 4 + 1][b] = v.y;
    es[dq * 4 + 2][b] = v.z; es[dq * 4 + 3][b] = v.w;
  }
  #pragma unroll
  for (int i = 0; i < 8; ++i) {
    const int fi = tid + i * 256;
    const int lr = fi >> 4, dq = fi & 15;
    const float4 v = *(const float4*)&labels[(size_t)lr * DO + d0 + dq * 4];
    ls[dq * 4 + 0][lr] = v.x; ls[dq * 4 + 1][lr] = v.y;
    ls[dq * 4 + 2][lr] = v.z; ls[dq * 4 + 3][lr] = v.w;
  }
  __syncthreads();

  const int tb = tid & 15;   // b-pair
  const int tl = tid >> 4;   // label-octet
  float acc[2][8] = {};

  for (int dd = 0; dd < 64; ++dd) {
    const float e0 = es[dd][tb * 2 + 0];
    const float e1 = es[dd][tb * 2 + 1];
    const float4 l0 = *(const float4*)&ls[dd][tl * 8];
    const float4 l1 = *(const float4*)&ls[dd][tl * 8 + 4];
    const float lv[8] = {l0.x, l0.y, l0.z, l0.w, l1.x, l1.y, l1.z, l1.w};
    #pragma unroll
    for (int j = 0; j < 8; ++j) {
      float t0 = fmaxf(lv[j] - e0, 0.f); acc[0][j] = fmaf(t0, t0, acc[0][j]);
      float t1 = fmaxf(lv[j] - e1, 0.f); acc[1][j] = fmaf(t1, t1, acc[1][j]);
    }
  }

  float* SPz = SP + (size_t)blockIdx.y * (Bn * NL);
  #pragma unroll
  for (int i = 0; i < 2; ++i) {
    const size_t base = (size_t)(b0 + tb * 2 + i) * NL + tl * 8;
    float4 v0 = {acc[i][0], acc[i][1], acc[i][2], acc[i][3]};
    float4 v1 = {acc[i][4], acc[i][5], acc[i][6], acc[i][7]};
    *(float4*)&SPz[base]     = v0;
    *(float4*)&SPz[base + 4] = v1;
  }
}

__global__ __launch_bounds__(256)
void score_reduce(const float* __restrict__ SP, float* __restrict__ out) {
  const size_t i4 = (size_t)blockIdx.x * 256 + threadIdx.x;
  f32x4 s = ((const f32x4*)SP)[i4];
  #pragma unroll
  for (int c = 1; c < 16; ++c) s += ((const f32x4*)SP)[(size_t)c * 32768 + i4];
  f32x4 o = {-sqrtf(s[0]), -sqrtf(s[1]), -sqrtf(s[2]), -sqrtf(s[3])};
  ((f32x4*)out)[i4] = o;
}

extern "C" void kernel_launch(void* const* d_in, const int* in_sizes, int n_in,
                              void* d_out, int out_size, void* d_ws, size_t ws_size,
                              hipStream_t stream) {
  const float* sbj  = (const float*)d_in[0];
  const float* obj  = (const float*)d_in[1];
  const float* W1   = (const float*)d_in[2];
  const float* b1   = (const float*)d_in[3];
  const float* W2   = (const float*)d_in[4];
  const float* b2   = (const float*)d_in[5];
  const float* labs = (const float*)d_in[6];
  float* scores = (float*)d_out;

  char* ws = (char*)d_ws;
  const bool big = ws_size >= (41ull << 20);
  // Lifetime-overlapped layout (all offsets MB):
  //   Abf [0,8)  W1t [8,16)  W2t [16,18)  H [18,20)
  //   P = big ? [24,40) : [20,24)     (partials; dead after its combine)
  //   E  [0,4)   (over dead Abf)      SP [4,12)  (over dead Abf/W1t)
  unsigned short* Abf = (unsigned short*)(ws);
  unsigned short* W1t = (unsigned short*)(ws + (8ull << 20));
  unsigned short* W2t = (unsigned short*)(ws + (16ull << 20));
  unsigned short* H   = (unsigned short*)(ws + (18ull << 20));
  float* P  = (float*)(ws + (big ? (24ull << 20) : (20ull << 20)));
  float* E  = (float*)(ws);
  float* SP = (float*)(ws + (4ull << 20));

  dim3 blk(256);
  concat_relu_bf16<<<dim3(2048), blk, 0, stream>>>(sbj, obj, Abf);
  transp_all<<<dim3(16, 80), blk, 0, stream>>>(W1, W2, W1t, W2t);

  if (big) {
    mfma_gemm<4, 4, 1024><<<dim3(8, 8, 4), blk, 0, stream>>>(Abf, W1t, P, K1);
    combine<4, true, true><<<dim3(Bn), blk, 0, stream>>>(P, b1, H);
    mfma_gemm<4, 4, 256><<<dim3(8, 8, 4), blk, 0, stream>>>(H, W2t, P, DO);
    combine<4, false, false><<<dim3(Bn), blk, 0, stream>>>(P, b2, E);
  } else {
    mfma_gemm<2, 2, 4096><<<dim3(16, 16, 1), blk, 0, stream>>>(Abf, W1t, P, K1);
    combine<1, true, true><<<dim3(Bn), blk, 0, stream>>>(P, b1, H);
    mfma_gemm<2, 2, 1024><<<dim3(16, 16, 1), blk, 0, stream>>>(H, W2t, P, DO);
    combine<1, false, false><<<dim3(Bn), blk, 0, stream>>>(P, b2, E);
  }

  score_partial<<<dim3(32, 16), blk, 0, stream>>>(E, labs, SP);
  score_reduce<<<dim3(128), blk, 0, stream>>>(SP, scores);
}

// Round 5
// 146.443 us; speedup vs baseline: 1.3419x; 1.0686x over previous
//
#include <hip/hip_runtime.h>
#include <math.h>

constexpr int Bn = 1024, DH = 2048, K1 = 4096, DO = 1024, NL = 128;
constexpr int MN = Bn * DO;  // 1M elements

typedef __bf16 bf16x8 __attribute__((ext_vector_type(8)));
typedef short  s16x8  __attribute__((ext_vector_type(8)));
typedef float  f32x4  __attribute__((ext_vector_type(4)));

__device__ __forceinline__ unsigned short f2bf(float f) {
  union { float f; unsigned u; } v; v.f = f;
  unsigned r = v.u + 0x7FFFu + ((v.u >> 16) & 1u);  // RNE
  return (unsigned short)(r >> 16);
}

// ---------- prep: concat+relu+bf16 (blocks 0..2047) and both W transposes
// (blocks 2048..3327) in ONE dispatch ----------
__global__ __launch_bounds__(256)
void prep(const float* __restrict__ sbj, const float* __restrict__ obj,
          const float* __restrict__ W1, const float* __restrict__ W2,
          unsigned short* __restrict__ Abf,
          unsigned short* __restrict__ W1t, unsigned short* __restrict__ W2t) {
  const int tid = threadIdx.x;
  if (blockIdx.x < 2048) {
    // concat(relu(sbj),relu(obj)) -> bf16 [1024][4096]
    const int t = blockIdx.x * 256 + tid;
    const int m = t >> 9;
    const int k = (t & 511) << 3;
    const float* src = (k < DH) ? sbj + (size_t)m * DH + k
                                : obj + (size_t)m * DH + (k - DH);
    const float4 a = ((const float4*)src)[0];
    const float4 b = ((const float4*)src)[1];
    uint4 o;
    o.x = (unsigned)f2bf(fmaxf(a.x, 0.f)) | ((unsigned)f2bf(fmaxf(a.y, 0.f)) << 16);
    o.y = (unsigned)f2bf(fmaxf(a.z, 0.f)) | ((unsigned)f2bf(fmaxf(a.w, 0.f)) << 16);
    o.z = (unsigned)f2bf(fmaxf(b.x, 0.f)) | ((unsigned)f2bf(fmaxf(b.y, 0.f)) << 16);
    o.w = (unsigned)f2bf(fmaxf(b.z, 0.f)) | ((unsigned)f2bf(fmaxf(b.w, 0.f)) << 16);
    *(uint4*)&Abf[(size_t)m * K1 + k] = o;
    return;
  }
  // transpose W1 [4096][1024] (by 0..63) / W2 [1024][1024] (by 64..79) -> [C][R] bf16
  __shared__ float tl[64][65];
  const int tb = blockIdx.x - 2048;
  int by = tb >> 4;
  const int c0 = (tb & 15) * 64;
  const float* in; unsigned short* out; int R;
  if (by < 64) { in = W1; out = W1t; R = K1; }
  else         { in = W2; out = W2t; R = DO; by -= 64; }
  const int r0 = by * 64;
  {
    const int rr = tid >> 4, cc = (tid & 15) * 4;
    #pragma unroll
    for (int i = 0; i < 4; ++i) {
      const float4 v = *(const float4*)&in[(size_t)(r0 + rr + i * 16) * DO + c0 + cc];
      tl[rr + i * 16][cc + 0] = v.x; tl[rr + i * 16][cc + 1] = v.y;
      tl[rr + i * 16][cc + 2] = v.z; tl[rr + i * 16][cc + 3] = v.w;
    }
  }
  __syncthreads();
  {
    const int r4 = (tid & 15) * 4;
    #pragma unroll
    for (int i = 0; i < 4; ++i) {
      const int cr = i * 16 + (tid >> 4);
      uint2 o;
      o.x = (unsigned)f2bf(tl[r4 + 0][cr]) | ((unsigned)f2bf(tl[r4 + 1][cr]) << 16);
      o.y = (unsigned)f2bf(tl[r4 + 2][cr]) | ((unsigned)f2bf(tl[r4 + 3][cr]) << 16);
      *(uint2*)&out[(size_t)(c0 + cr) * R + r0 + r4] = o;
    }
  }
}

// ---------- MFMA GEMM: 64x64 tile, 256 thr (4 waves), BK=128 single-buffer,
// in-block k-split over 4 waves (LDS tree-reduce), block split-K via blockIdx.z.
// Grid 16x16xZ = 1024 blocks -> 4 blocks/CU for cross-block latency overlap.
// Writes fp32 partials P[z][1024][1024]. ----------
template <int KSLICE>
__global__ __launch_bounds__(256, 4)
void mfma_gemm(const unsigned short* __restrict__ A,
               const unsigned short* __restrict__ Bt,
               float* __restrict__ P, int K) {
  // 32 KB LDS: LA = 16 KB (64 rows x 16 chunks x 8 bf16), LB same.
  __shared__ __align__(16) unsigned short smem[2 * 64 * 128];
  unsigned short* LA = smem;
  unsigned short* LB = smem + 64 * 128;

  const int tid = threadIdx.x;
  const int w = tid >> 6, l = tid & 63;
  const int m0 = blockIdx.y * 64, n0 = blockIdx.x * 64;
  const int kb = blockIdx.z * KSLICE;

  f32x4 acc[4][4] = {};

  constexpr int NIT = KSLICE / 128;
  for (int it = 0; it < NIT; ++it) {
    const int k0 = kb + it * 128;
    // stage A,B tiles (64 rows x 16 chunks-of-8): 4+4 DMA/thread, 16B each.
    // slot c = i*256 + tid is wave-contiguous (tid = w*64+l) -> valid DMA dest.
    #pragma unroll
    for (int i = 0; i < 4; ++i) {
      const int c = i * 256 + tid, m = c >> 4, kc = c & 15;
      const int kcg = (kc & 8) | ((kc & 7) ^ (m & 7));
      __builtin_amdgcn_global_load_lds(
          (const __attribute__((address_space(1))) unsigned int*)(A + (size_t)(m0 + m) * K + k0 + kcg * 8),
          (__attribute__((address_space(3))) unsigned int*)&LA[c * 8], 16, 0, 0);
    }
    #pragma unroll
    for (int i = 0; i < 4; ++i) {
      const int c = i * 256 + tid, n = c >> 4, kc = c & 15;
      const int kcg = (kc & 8) | ((kc & 7) ^ (n & 7));
      __builtin_amdgcn_global_load_lds(
          (const __attribute__((address_space(1))) unsigned int*)(Bt + (size_t)(n0 + n) * K + k0 + kcg * 8),
          (__attribute__((address_space(3))) unsigned int*)&LB[c * 8], 16, 0, 0);
    }
    __syncthreads();

    // wave w owns k in [w*32, w*32+32): logical chunks kcq = w*4 + (l>>4)
    const int kcq = w * 4 + (l >> 4);
    bf16x8 af[4], bfr[4];
    #pragma unroll
    for (int i = 0; i < 4; ++i) {
      const int r = i * 16 + (l & 15);
      const int kca = (kcq & 8) | ((kcq & 7) ^ (r & 7));
      af[i]  = __builtin_bit_cast(bf16x8, *(const s16x8*)&LA[(r * 16 + kca) * 8]);
      bfr[i] = __builtin_bit_cast(bf16x8, *(const s16x8*)&LB[(r * 16 + kca) * 8]);
    }
    #pragma unroll
    for (int i = 0; i < 4; ++i)
      #pragma unroll
      for (int j = 0; j < 4; ++j)
        acc[i][j] = __builtin_amdgcn_mfma_f32_16x16x32_bf16(af[i], bfr[j], acc[i][j], 0, 0, 0);
    __syncthreads();
  }

  // ---- 4-wave k-split tree reduction in LDS (reuse smem: 32 KB = 8192 f32) ----
  float* red = (float*)smem;
  auto writeacc = [&](float* dst) {
    #pragma unroll
    for (int i = 0; i < 4; ++i)
      #pragma unroll
      for (int j = 0; j < 4; ++j)
        *(f32x4*)&dst[((i * 4 + j) * 64 + l) * 4] = acc[i][j];
  };
  auto addacc = [&](const float* src) {
    #pragma unroll
    for (int i = 0; i < 4; ++i)
      #pragma unroll
      for (int j = 0; j < 4; ++j)
        acc[i][j] += *(const f32x4*)&src[((i * 4 + j) * 64 + l) * 4];
  };
  if (w >= 2) writeacc(red + (w - 2) * 4096);
  __syncthreads();
  if (w < 2) addacc(red + w * 4096);
  __syncthreads();
  if (w == 1) writeacc(red);
  __syncthreads();
  if (w != 0) return;
  addacc(red);

  // wave 0 stores fp32 partial tile (C/D: col=l&15 -> n, row=(l>>4)*4+r -> m)
  float* Pz = P + (size_t)blockIdx.z * MN;
  #pragma unroll
  for (int i = 0; i < 4; ++i) {
    #pragma unroll
    for (int r = 0; r < 4; ++r) {
      const int m = m0 + i * 16 + (l >> 4) * 4 + r;
      #pragma unroll
      for (int j = 0; j < 4; ++j) {
        const int n = n0 + j * 16 + (l & 15);
        Pz[(size_t)m * DO + n] = acc[i][j][r];
      }
    }
  }
}

// ---------- combine: out = act(sum_z P[z] + bias) ----------
template <int KS, bool RELU, bool OUT_BF16>
__global__ __launch_bounds__(256)
void combine(const float* __restrict__ P, const float* __restrict__ bias,
             void* __restrict__ out) {
  const int row = blockIdx.x, t = threadIdx.x;
  const size_t i4 = (size_t)row * 256 + t;
  f32x4 s = ((const f32x4*)P)[i4];
  #pragma unroll
  for (int c = 1; c < KS; ++c) s += ((const f32x4*)P)[(size_t)c * (MN / 4) + i4];
  const f32x4 bb = *(const f32x4*)&bias[t * 4];
  s += bb;
  if (RELU) {
    s[0] = fmaxf(s[0], 0.f); s[1] = fmaxf(s[1], 0.f);
    s[2] = fmaxf(s[2], 0.f); s[3] = fmaxf(s[3], 0.f);
  }
  if (OUT_BF16) {
    uint2 o;
    o.x = (unsigned)f2bf(s[0]) | ((unsigned)f2bf(s[1]) << 16);
    o.y = (unsigned)f2bf(s[2]) | ((unsigned)f2bf(s[3]) << 16);
    *(uint2*)((unsigned short*)out + (size_t)row * DO + t * 4) = o;
  } else {
    *(f32x4*)((float*)out + (size_t)row * DO + t * 4) = s;
  }
}

// ---------- scores: d-split partials (plain stores) + reduce ----------
__global__ __launch_bounds__(256)
void score_partial(const float* __restrict__ emb, const float* __restrict__ labels,
                   float* __restrict__ SP) {
  __shared__ float es[64][33];   // [d][b]
  __shared__ float ls[64][132];  // [d][l]
  const int tid = threadIdx.x;
  const int b0 = blockIdx.x * 32;
  const int d0 = blockIdx.y * 64;

  #pragma unroll
  for (int i = 0; i < 2; ++i) {
    const int fi = tid + i * 256;
    const int b = fi >> 4, dq = fi & 15;
    const float4 v = *(const float4*)&emb[(size_t)(b0 + b) * DO + d0 + dq * 4];
    es[dq * 4 + 0][b] = v.x; es[dq * 4 + 1][b] = v.y;
    es[dq * 4 + 2][b] = v.z; es[dq * 4 + 3][b] = v.w;
  }
  #pragma unroll
  for (int i = 0; i < 8; ++i) {
    const int fi = tid + i * 256;
    const int lr = fi >> 4, dq = fi & 15;
    const float4 v = *(const float4*)&labels[(size_t)lr * DO + d0 + dq * 4];
    ls[dq * 4 + 0][lr] = v.x; ls[dq * 4 + 1][lr] = v.y;
    ls[dq * 4 + 2][lr] = v.z; ls[dq * 4 + 3][lr] = v.w;
  }
  __syncthreads();

  const int tb = tid & 15;   // b-pair
  const int tl = tid >> 4;   // label-octet
  float acc[2][8] = {};

  for (int dd = 0; dd < 64; ++dd) {
    const float e0 = es[dd][tb * 2 + 0];
    const float e1 = es[dd][tb * 2 + 1];
    const float4 l0 = *(const float4*)&ls[dd][tl * 8];
    const float4 l1 = *(const float4*)&ls[dd][tl * 8 + 4];
    const float lv[8] = {l0.x, l0.y, l0.z, l0.w, l1.x, l1.y, l1.z, l1.w};
    #pragma unroll
    for (int j = 0; j < 8; ++j) {
      float t0 = fmaxf(lv[j] - e0, 0.f); acc[0][j] = fmaf(t0, t0, acc[0][j]);
      float t1 = fmaxf(lv[j] - e1, 0.f); acc[1][j] = fmaf(t1, t1, acc[1][j]);
    }
  }

  float* SPz = SP + (size_t)blockIdx.y * (Bn * NL);
  #pragma unroll
  for (int i = 0; i < 2; ++i) {
    const size_t base = (size_t)(b0 + tb * 2 + i) * NL + tl * 8;
    float4 v0 = {acc[i][0], acc[i][1], acc[i][2], acc[i][3]};
    float4 v1 = {acc[i][4], acc[i][5], acc[i][6], acc[i][7]};
    *(float4*)&SPz[base]     = v0;
    *(float4*)&SPz[base + 4] = v1;
  }
}

__global__ __launch_bounds__(256)
void score_reduce(const float* __restrict__ SP, float* __restrict__ out) {
  const size_t i4 = (size_t)blockIdx.x * 256 + threadIdx.x;
  f32x4 s = ((const f32x4*)SP)[i4];
  #pragma unroll
  for (int c = 1; c < 16; ++c) s += ((const f32x4*)SP)[(size_t)c * 32768 + i4];
  f32x4 o = {-sqrtf(s[0]), -sqrtf(s[1]), -sqrtf(s[2]), -sqrtf(s[3])};
  ((f32x4*)out)[i4] = o;
}

extern "C" void kernel_launch(void* const* d_in, const int* in_sizes, int n_in,
                              void* d_out, int out_size, void* d_ws, size_t ws_size,
                              hipStream_t stream) {
  const float* sbj  = (const float*)d_in[0];
  const float* obj  = (const float*)d_in[1];
  const float* W1   = (const float*)d_in[2];
  const float* b1   = (const float*)d_in[3];
  const float* W2   = (const float*)d_in[4];
  const float* b2   = (const float*)d_in[5];
  const float* labs = (const float*)d_in[6];
  float* scores = (float*)d_out;

  char* ws = (char*)d_ws;
  // Layout (MB): Abf [0,8)  W1t [8,16)  W2t [16,18)  H [18,20)
  //              P [24,40)  E [40,44)  SP [44,52)
  unsigned short* Abf = (unsigned short*)(ws);
  unsigned short* W1t = (unsigned short*)(ws + (8ull << 20));
  unsigned short* W2t = (unsigned short*)(ws + (16ull << 20));
  unsigned short* H   = (unsigned short*)(ws + (18ull << 20));
  float* P  = (float*)(ws + (24ull << 20));
  float* E  = (float*)(ws + (40ull << 20));
  float* SP = (float*)(ws + (44ull << 20));

  dim3 blk(256);
  prep<<<dim3(2048 + 1280), blk, 0, stream>>>(sbj, obj, W1, W2, Abf, W1t, W2t);

  // GEMM1: K=4096, split-K=4 (slices of 1024) -> 1024 blocks (4/CU)
  mfma_gemm<1024><<<dim3(16, 16, 4), blk, 0, stream>>>(Abf, W1t, P, K1);
  combine<4, true, true><<<dim3(Bn), blk, 0, stream>>>(P, b1, H);
  // GEMM2: K=1024, split-K=4 (slices of 256) -> 1024 blocks
  mfma_gemm<256><<<dim3(16, 16, 4), blk, 0, stream>>>(H, W2t, P, DO);
  combine<4, false, false><<<dim3(Bn), blk, 0, stream>>>(P, b2, E);

  score_partial<<<dim3(32, 16), blk, 0, stream>>>(E, labs, SP);
  score_reduce<<<dim3(128), blk, 0, stream>>>(SP, scores);
}